// Round 8
// baseline (519.931 us; speedup 1.0000x reference)
//
#include <hip/hip_runtime.h>
#include <math.h>

// AAModel round 8: M=64 conv via WAVE-PAIR TILE SHARING.
// Waves {0,1} process region-half A of W2, waves {2,3} region-half B; within a
// pair both waves stream the SAME tiles (wave owns edges 0-31 vs 32-63), so
// the pair's second wave hits L1/MSHR-merge -> W2 crosses L2 once per 64-edge
// block (half of round 6's traffic). Per-wave register shape is round 6's
// proven no-spill layout: ag[2][5], 1-deep prefetch, register-complete TP
// accumulators, native-atomic scatter. No waves-per-EU pin (round 4/5 lesson),
// no 4-tile A-frags (round 7 lesson).

constexpr float SQ3f = 1.7320508075688772f;
constexpr float INV1 = 0.14433756729740643f;  // 1/sqrt(48)
constexpr float NAc  = 0.10206207261596575f;  // 1/sqrt(2*48)
constexpr float NBc  = 0.22360679774997896f;  // 1/sqrt(2*10)
constexpr float C20  = 0.22360679774997896f;  // 1/sqrt(20)
constexpr float RATIO= 1.2649110640673518f;   // (NBc/sqrt3)/NAc
constexpr float DSP  = 30.0f/31.0f;
constexpr float GCOEF= -0.5f/(DSP*DSP);

typedef __attribute__((ext_vector_type(8))) short bf16x8;
typedef __attribute__((ext_vector_type(4))) float f32x4;

__device__ __forceinline__ unsigned short f2bf(float x) {
    unsigned u = __builtin_bit_cast(unsigned, x);
    u += 0x7fffu + ((u >> 16) & 1u);     // RNE
    return (unsigned short)(u >> 16);
}

// tile/lane-slot -> original W2 column (or -1 = padding lane)
__device__ __forceinline__ int colmap(int layer, int t, int lm) {
    if (layer == 0) return t*16 + lm;                           // W1 identity
    if (layer == 1) {
        if (t < 144) { const int og=t/48, i=t-og*48; return i*48 + og*16 + lm; }      // w00
        const int i = t-144; return (lm<10) ? 2304 + i*10 + lm : -1;                  // w01
    }
    if (t < 144) { const int og=t/48, i=t-og*48; return i*48 + og*16 + lm; }          // w00
    if (t < 174) { const int s=t-144, og=s/10, i=s-og*10; return 2884 + i*48 + og*16 + lm; } // w11s
    if (t < 222) { const int i=t-174; return (lm<10) ? 2304 + i*10 + lm : -1; }       // w01
    if (t < 232) { const int i=t-222; return (lm<10) ? 2784 + i*10 + lm : -1; }       // w10
    { const int i=t-232; return (lm<10) ? 3364 + i*10 + lm : -1; }                    // w11p
}

__global__ __launch_bounds__(256)
void cvt_swz(const float* __restrict__ W, const float* __restrict__ bias,
             short* __restrict__ Wsw, int ncol, int ntile, int layer)
{
    const int gid = blockIdx.x*256 + threadIdx.x;
    const int g = gid >> 6, lane = gid & 63;
    if (g >= ntile*5) return;
    const int tile = g/5, ks = g - tile*5;
    const int c  = colmap(layer, tile, lane & 15);
    const int k0 = ks*32 + (lane >> 4)*8;
    union { uint4 u4; unsigned short h[8]; } pk;
    #pragma unroll
    for (int j=0;j<8;j++) {
        const int k = k0 + j;
        float v = 0.f;
        if (c >= 0) {
            if (k < 144)       v = W[(size_t)k*ncol + c];
            else if (k == 144) v = bias[c];
        }
        pk.h[j] = f2bf(v);
    }
    *(uint4*)&Wsw[((size_t)g*64 + lane)*8] = pk.u4;
}

// ----------------------------------------------------------------------------
__global__ __launch_bounds__(256)
void edge_kernel(const float* __restrict__ pos, const float* __restrict__ sigma,
                 const int* __restrict__ ei,
                 const float* __restrict__ W1, const float* __restrict__ b1,
                 const float* __restrict__ W2, const float* __restrict__ b2,
                 float* __restrict__ edge_emb, float* __restrict__ sh1buf,
                 int* __restrict__ deg, int E)
{
    __shared__ float inl[4][64];
    __shared__ float hidl[4][48];
    const int w    = threadIdx.x >> 6;
    const int lane = threadIdx.x & 63;
    const int e    = blockIdx.x*4 + w;
    const bool valid = (e < E);
    const int ec = valid ? e : 0;
    const int src = ei[ec], dst = ei[E+ec];
    const float vx = pos[dst*3+0]-pos[src*3+0];
    const float vy = pos[dst*3+1]-pos[src*3+1];
    const float vz = pos[dst*3+2]-pos[src*3+2];
    const float d  = sqrtf(vx*vx+vy*vy+vz*vz);
    const float si = SQ3f/(d+1e-8f);
    const float s0 = vx*si, s1 = vy*si, s2 = vz*si;
    if (lane < 32) {
        inl[w][lane] = sigma[src*32+lane];
    } else {
        const float off  = (float)(lane-32)*DSP;
        const float diff = d - off;
        inl[w][lane] = expf(GCOEF*diff*diff);
    }
    __syncthreads();
    if (lane < 48) {
        float a = b1[lane];
        #pragma unroll 8
        for (int j=0;j<64;j++) a = fmaf(inl[w][j], W1[j*48+lane], a);
        hidl[w][lane] = fmaxf(a, 0.f);
    }
    __syncthreads();
    if (valid) {
        if (lane < 48) {
            float a = b2[lane];
            #pragma unroll 8
            for (int j=0;j<48;j++) a = fmaf(hidl[w][j], W2[j*48+lane], a);
            edge_emb[e*48+lane] = a;
        }
        if (lane == 0) atomicAdd(&deg[dst], 1);
        if (lane < 3)  sh1buf[e*4+lane] = (lane==0)?s0:((lane==1)?s1:s2);
    }
}

// ----------------------------------------------------------------------------
__device__ __forceinline__ void load_bfrag(const short* __restrict__ Wsw,
                                           int tile, int lane, bf16x8 (&b)[5]) {
    #pragma unroll
    for (int ks=0; ks<5; ks++)
        b[ks] = *(const bf16x8*)&Wsw[((size_t)(tile*5+ks)*64 + lane)*8];
}

__device__ __forceinline__ void mfma5(const bf16x8 (&ag)[2][5], const bf16x8 (&b)[5],
                                      f32x4& a0, f32x4& a1) {
    a0 = (f32x4){0.f,0.f,0.f,0.f};
    a1 = (f32x4){0.f,0.f,0.f,0.f};
    #pragma unroll
    for (int ks=0; ks<5; ks++) {
        a0 = __builtin_amdgcn_mfma_f32_16x16x32_bf16(ag[0][ks], b[ks], a0, 0,0,0);
        a1 = __builtin_amdgcn_mfma_f32_16x16x32_bf16(ag[1][ks], b[ks], a1, 0,0,0);
    }
}

// tiles base..base+count, single-step prefetch (round-3/6-proven pressure)
template<typename F>
__device__ __forceinline__ void region1(const short* __restrict__ Wsw, int base,
                                        int count, int lane,
                                        const bf16x8 (&ag)[2][5], F&& upd)
{
    bf16x8 bc[5], bn[5];
    load_bfrag(Wsw, base, lane, bc);
    for (int i=0; i<count; ++i) {
        if (i+1 < count) load_bfrag(Wsw, base+i+1, lane, bn);
        f32x4 a0, a1;
        mfma5(ag, bc, a0, a1);
        upd(i, a0, a1);
        #pragma unroll
        for (int ks=0; ks<5; ks++) bc[ks] = bn[ks];
    }
}

// ----------------------------------------------------------------------------
template<int LAYER>
__global__ __launch_bounds__(256)
void conv_kernel(const float* __restrict__ edge_emb, const float* __restrict__ sh1buf,
                 const int* __restrict__ ei,
                 const float* __restrict__ sin_, const float* __restrict__ vin,
                 const short* __restrict__ W1sw, const short* __restrict__ W2sw,
                 float* __restrict__ outS, float* __restrict__ outV, int E)
{
    __shared__ __align__(16) short pool[64*192];  // ea staged, then hid (bf16 swz)
    __shared__ __align__(16) float xsT[48][68];   // [chan][edge]
    __shared__ float sh1l[64][4];
    __shared__ int   srcl[64], dstl[64];
    __shared__ __align__(16) float xvT[LAYER==2 ? 30 : 1][68];
    __shared__ __align__(16) float uT [LAYER==2 ? 10 : 1][68];
    __shared__ __align__(16) float cvT[LAYER==2 ? 30 : 1][68];

    const int t  = threadIdx.x;
    const int eb = blockIdx.x * 64;

    if (t < 64) {
        const int ge = eb + t; const int gc = (ge < E) ? ge : (E-1);
        srcl[t] = ei[gc]; dstl[t] = ei[E+gc];
    }
    {
        const int e = t >> 2, k = t & 3;
        const int ge = eb + e; const int gc = (ge<E)?ge:(E-1);
        sh1l[e][k] = sh1buf[gc*4 + k];
    }
    __syncthreads();

    // ---- stage ea -> bf16 swizzled pool (+ fp32 xsT fill)
    for (int p = t; p < 64*24; p += 256) {
        const int m = p / 24, s = p - m*24;
        const int k0 = s*8;
        float vals[8] = {0.f,0.f,0.f,0.f,0.f,0.f,0.f,0.f};
        if (k0 < 48) {
            const int ge = eb + m; const int gc = (ge<E)?ge:(E-1);
            const float4 a = *(const float4*)&edge_emb[gc*48 + k0];
            const float4 b = *(const float4*)&edge_emb[gc*48 + k0 + 4];
            vals[0]=a.x; vals[1]=a.y; vals[2]=a.z; vals[3]=a.w;
            vals[4]=b.x; vals[5]=b.y; vals[6]=b.z; vals[7]=b.w;
        } else if (k0 < 96) {
            const float4 a = *(const float4*)&sin_[srcl[m]*48 + (k0-48)];
            const float4 b = *(const float4*)&sin_[srcl[m]*48 + (k0-48) + 4];
            vals[0]=a.x; vals[1]=a.y; vals[2]=a.z; vals[3]=a.w;
            vals[4]=b.x; vals[5]=b.y; vals[6]=b.z; vals[7]=b.w;
            #pragma unroll
            for (int j=0;j<8;j++) xsT[k0-48+j][m] = vals[j];
        } else if (k0 < 144) {
            const float4 a = *(const float4*)&sin_[dstl[m]*48 + (k0-96)];
            const float4 b = *(const float4*)&sin_[dstl[m]*48 + (k0-96) + 4];
            vals[0]=a.x; vals[1]=a.y; vals[2]=a.z; vals[3]=a.w;
            vals[4]=b.x; vals[5]=b.y; vals[6]=b.z; vals[7]=b.w;
        } else if (k0 == 144) {
            vals[0] = 1.f;                       // bias row for GEMM1
        }
        union { uint4 u4; unsigned short h[8]; } pk;
        #pragma unroll
        for (int j=0;j<8;j++) pk.h[j] = f2bf(vals[j]);
        *(uint4*)&pool[m*192 + ((s ^ (m&7))*8)] = pk.u4;
    }
    if (LAYER==2) {
        for (int p=t; p<640; p+=256) {
            const int i = p >> 6, e = p & 63;
            const float x0 = vin[srcl[e]*30 + i*3+0];
            const float x1 = vin[srcl[e]*30 + i*3+1];
            const float x2 = vin[srcl[e]*30 + i*3+2];
            const float h0=sh1l[e][0], h1=sh1l[e][1], h2=sh1l[e][2];
            xvT[i*3+0][e]=x0; xvT[i*3+1][e]=x1; xvT[i*3+2][e]=x2;
            uT[i][e] = x0*h0 + x1*h1 + x2*h2;
            cvT[i*3+0][e] = x1*h2 - x2*h1;
            cvT[i*3+1][e] = x2*h0 - x0*h2;
            cvT[i*3+2][e] = x0*h1 - x1*h0;
        }
    }
    __syncthreads();

    const int wv = t >> 6, lane = t & 63;
    const int lm = lane & 15, lk = lane >> 4, lk4 = lk*4;

    // ---- GEMM1: hid = relu(ea @ W1), reg accumulate, overwrite pool
    {
        bf16x8 af[4][5];
        #pragma unroll
        for (int mt=0; mt<4; mt++) {
            const int m = mt*16 + lm;
            #pragma unroll
            for (int ks=0; ks<5; ks++)
                af[mt][ks] = *(const bf16x8*)&pool[m*192 + (((ks*4+lk) ^ (m&7))*8)];
        }
        f32x4 acc[3][4];
        #pragma unroll
        for (int j=0; j<3; j++) {
            const int nt = wv + j*4;
            if (nt < 9) {
                bf16x8 bw[5];
                load_bfrag(W1sw, nt, lane, bw);
                #pragma unroll
                for (int mt=0; mt<4; mt++) acc[j][mt] = (f32x4){0.f,0.f,0.f,0.f};
                #pragma unroll
                for (int ks=0; ks<5; ks++)
                    #pragma unroll
                    for (int mt=0; mt<4; mt++)
                        acc[j][mt] = __builtin_amdgcn_mfma_f32_16x16x32_bf16(af[mt][ks], bw[ks], acc[j][mt], 0,0,0);
            }
        }
        __syncthreads();   // staged ea fully consumed
        #pragma unroll
        for (int j=0; j<3; j++) {
            const int nt = wv + j*4;
            if (nt < 9) {
                const int c = nt*16 + lm;
                #pragma unroll
                for (int mt=0; mt<4; mt++)
                    #pragma unroll
                    for (int r=0; r<4; r++) {
                        const int m = mt*16 + lk4 + r;
                        pool[m*192 + (((c>>3) ^ (m&7))*8) + (c&7)] = (short)f2bf(fmaxf(acc[j][mt][r], 0.f));
                    }
            }
        }
        if (t < 128) {  // bias rows k=144..159
            const int m = t >> 1, s = 18 + (t & 1);
            union { uint4 u4; unsigned short h[8]; } pk;
            pk.u4.x = pk.u4.y = pk.u4.z = pk.u4.w = 0u;
            if (s == 18) pk.h[0] = f2bf(1.f);
            *(uint4*)&pool[m*192 + ((s ^ (m&7))*8)] = pk.u4;
        }
    }
    __syncthreads();

    // ---- main: wave pair shares tile stream; wave owns 32 edges
    const int pair = wv >> 1;        // 0: waves 0,1   1: waves 2,3
    const int half = wv & 1;         // edge half: 0 -> edges 0..31, 1 -> 32..63
    const int e0b  = half*32;        // this wave's edge base
    const int col0 = e0b + lk4;      // xsT column base for mtl=0

    bf16x8 ag[2][5];
    #pragma unroll
    for (int mtl=0; mtl<2; mtl++) {
        const int m = e0b + mtl*16 + lm;
        #pragma unroll
        for (int ks=0; ks<5; ks++)
            ag[mtl][ks] = *(const bf16x8*)&pool[m*192 + (((ks*4+lk) ^ (m&7))*8)];
    }

    const float sScale = (LAYER==1) ? INV1 : NAc;
    const int   sStrd  = (LAYER==1) ? 48 : 108;

    // scalar-output group helper: accumulate + scatter for one og
    auto do_og = [&](int og) {
        float ms[2][4] = {{0.f,0.f,0.f,0.f},{0.f,0.f,0.f,0.f}};
        region1(W2sw, og*48, 48, lane, ag, [&](int i, f32x4 a0, f32x4 a1) {
            const f32x4 x0 = *(const f32x4*)&xsT[i][col0];
            const f32x4 x1 = *(const f32x4*)&xsT[i][col0+16];
            #pragma unroll
            for (int r=0;r<4;r++) {
                ms[0][r] = fmaf(a0[r], x0[r], ms[0][r]);
                ms[1][r] = fmaf(a1[r], x1[r], ms[1][r]);
            }
        });
        if (LAYER==2) {
            region1(W2sw, 144 + og*10, 10, lane, ag, [&](int i, f32x4 a0, f32x4 a1) {
                const f32x4 u0 = *(const f32x4*)&uT[i][col0];
                const f32x4 u1 = *(const f32x4*)&uT[i][col0+16];
                #pragma unroll
                for (int r=0;r<4;r++) {
                    ms[0][r] = fmaf(a0[r]*RATIO, u0[r], ms[0][r]);
                    ms[1][r] = fmaf(a1[r]*RATIO, u1[r], ms[1][r]);
                }
            });
        }
        const int o = og*16 + lm;
        #pragma unroll
        for (int mtl=0; mtl<2; mtl++)
            #pragma unroll
            for (int r=0;r<4;r++) {
                const int e = e0b + mtl*16 + lk4 + r;
                if (eb+e < E) unsafeAtomicAdd(&outS[(size_t)dstl[e]*sStrd + o], ms[mtl][r]*sScale);
            }
    };

    if (pair == 0) {
        do_og(0);
        do_og(1);
    } else {
        do_og(2);
        // ---- vector-channel outputs
        float vc[2][4] = {{0.f,0.f,0.f,0.f},{0.f,0.f,0.f,0.f}};
        region1(W2sw, (LAYER==1) ? 144 : 174, 48, lane, ag, [&](int i, f32x4 a0, f32x4 a1) {
            const f32x4 x0 = *(const f32x4*)&xsT[i][col0];
            const f32x4 x1 = *(const f32x4*)&xsT[i][col0+16];
            #pragma unroll
            for (int r=0;r<4;r++) {
                vc[0][r] = fmaf(a0[r], x0[r], vc[0][r]);
                vc[1][r] = fmaf(a1[r], x1[r], vc[1][r]);
            }
        });
        if (LAYER==1) {
            if (lm < 10) {
                #pragma unroll
                for (int mtl=0; mtl<2; mtl++)
                    #pragma unroll
                    for (int r=0;r<4;r++) {
                        const int e = e0b + mtl*16 + lk4 + r;
                        if (eb+e < E) {
                            const float v = vc[mtl][r]*INV1;
                            #pragma unroll
                            for (int d=0; d<3; d++)
                                unsafeAtomicAdd(&outV[(size_t)dstl[e]*30 + lm*3 + d], v*sh1l[e][d]);
                        }
                    }
            }
        } else {
            {   // w10 (xvT), combined scatter with vc
                float m3[2][4][3] = {};
                region1(W2sw, 222, 10, lane, ag, [&](int i, f32x4 a0, f32x4 a1) {
                    #pragma unroll
                    for (int d=0; d<3; d++) {
                        const f32x4 x0 = *(const f32x4*)&xvT[i*3+d][col0];
                        const f32x4 x1 = *(const f32x4*)&xvT[i*3+d][col0+16];
                        #pragma unroll
                        for (int r=0;r<4;r++) {
                            m3[0][r][d] = fmaf(a0[r], x0[r], m3[0][r][d]);
                            m3[1][r][d] = fmaf(a1[r], x1[r], m3[1][r][d]);
                        }
                    }
                });
                if (lm < 10) {
                    #pragma unroll
                    for (int mtl=0; mtl<2; mtl++)
                        #pragma unroll
                        for (int r=0;r<4;r++) {
                            const int e = e0b + mtl*16 + lk4 + r;
                            if (eb+e < E) {
                                const float v = vc[mtl][r]*NAc;
                                #pragma unroll
                                for (int d=0; d<3; d++)
                                    unsafeAtomicAdd(&outS[(size_t)dstl[e]*108 + 48 + lm*3 + d],
                                                    v*sh1l[e][d] + m3[mtl][r][d]*NBc);
                            }
                        }
                }
            }
            {   // w11p (cvT)
                float m3[2][4][3] = {};
                region1(W2sw, 232, 10, lane, ag, [&](int i, f32x4 a0, f32x4 a1) {
                    #pragma unroll
                    for (int d=0; d<3; d++) {
                        const f32x4 x0 = *(const f32x4*)&cvT[i*3+d][col0];
                        const f32x4 x1 = *(const f32x4*)&cvT[i*3+d][col0+16];
                        #pragma unroll
                        for (int r=0;r<4;r++) {
                            m3[0][r][d] = fmaf(a0[r], x0[r], m3[0][r][d]);
                            m3[1][r][d] = fmaf(a1[r], x1[r], m3[1][r][d]);
                        }
                    }
                });
                if (lm < 10) {
                    #pragma unroll
                    for (int mtl=0; mtl<2; mtl++)
                        #pragma unroll
                        for (int r=0;r<4;r++) {
                            const int e = e0b + mtl*16 + lk4 + r;
                            if (eb+e < E) {
                                #pragma unroll
                                for (int d=0; d<3; d++)
                                    unsafeAtomicAdd(&outS[(size_t)dstl[e]*108 + 78 + lm*3 + d],
                                                    m3[mtl][r][d]*C20);
                            }
                        }
                }
            }
        }
    }
}

// ----------------------------------------------------------------------------
__global__ __launch_bounds__(256)
void fin1_kernel(const float* __restrict__ node_s, const int* __restrict__ deg,
                 float* __restrict__ s1, float* __restrict__ v1, int Nn)
{
    const int p = blockIdx.x*256 + threadIdx.x;
    const int totS = Nn*48;
    if (p < totS) {
        const int n = p/48;
        const int dgi = deg[n];
        const float dg = (float)(dgi > 1 ? dgi : 1);
        s1[p] = node_s[p] + s1[p]/dg;
    } else {
        const int q = p - totS;
        if (q < Nn*30) {
            const int n = q/30;
            const int dgi = deg[n];
            const float dg = (float)(dgi > 1 ? dgi : 1);
            v1[q] = v1[q]/dg;
        }
    }
}

__global__ __launch_bounds__(256)
void fin2_kernel(const float* __restrict__ s1, const float* __restrict__ v1,
                 const int* __restrict__ deg, float* __restrict__ out, int Nn)
{
    const int p = blockIdx.x*256 + threadIdx.x;
    if (p >= Nn*108) return;
    const int n = p/108, c = p - n*108;
    const int dgi = deg[n];
    const float dg = (float)(dgi > 1 ? dgi : 1);
    const float acc = out[p]/dg;
    if (c < 48)      out[p] = s1[n*48+c] + acc;
    else if (c < 78) out[p] = v1[n*30 + (c-48)] + acc;
    else             out[p] = acc;
}

// ----------------------------------------------------------------------------
extern "C" void kernel_launch(void* const* d_in, const int* in_sizes, int n_in,
                              void* d_out, int out_size, void* d_ws, size_t ws_size,
                              hipStream_t stream)
{
    const float* pos    = (const float*)d_in[0];
    const float* sigma  = (const float*)d_in[1];
    const float* node_s = (const float*)d_in[2];
    const float* eW1  = (const float*)d_in[3];
    const float* eb1  = (const float*)d_in[4];
    const float* eW2  = (const float*)d_in[5];
    const float* eb2  = (const float*)d_in[6];
    const float* f1W1 = (const float*)d_in[7];
    const float* f1b1 = (const float*)d_in[8];
    const float* f1W2 = (const float*)d_in[9];
    const float* f1b2 = (const float*)d_in[10];
    const float* f2W1 = (const float*)d_in[11];
    const float* f2b1 = (const float*)d_in[12];
    const float* f2W2 = (const float*)d_in[13];
    const float* f2b2 = (const float*)d_in[14];
    const int*   ei   = (const int*)d_in[15];
    const int Nn = in_sizes[0]/3;
    const int E  = in_sizes[15]/2;
    float* out = (float*)d_out;

    char* ws = (char*)d_ws;
    float* edge_emb = (float*)ws;  ws += (size_t)E*48*sizeof(float);
    float* sh1buf   = (float*)ws;  ws += (size_t)E*4*sizeof(float);
    float* s1       = (float*)ws;  ws += (size_t)Nn*48*sizeof(float);
    float* v1       = (float*)ws;  ws += (size_t)Nn*30*sizeof(float);
    int*   deg      = (int*)ws;    ws += (size_t)Nn*sizeof(int);
    short* W1sw     = (short*)ws;  ws += (size_t)9*5*64*8*sizeof(short);
    short* W2sw     = (short*)ws;  ws += (size_t)242*5*64*8*sizeof(short);

    hipMemsetAsync(s1,  0, (size_t)Nn*48*sizeof(float), stream);
    hipMemsetAsync(v1,  0, (size_t)Nn*30*sizeof(float), stream);
    hipMemsetAsync(deg, 0, (size_t)Nn*sizeof(int),      stream);
    hipMemsetAsync(out, 0, (size_t)Nn*108*sizeof(float), stream);

    edge_kernel<<<(E+3)/4, 256, 0, stream>>>(pos, sigma, ei, eW1, eb1, eW2, eb2,
                                             edge_emb, sh1buf, deg, E);

    cvt_swz<<<(9*5*64+255)/256,   256, 0, stream>>>(f1W1, f1b1, W1sw, 144, 9, 0);
    cvt_swz<<<(192*5*64+255)/256, 256, 0, stream>>>(f1W2, f1b2, W2sw, 2784, 192, 1);

    conv_kernel<1><<<(E+63)/64, 256, 0, stream>>>(edge_emb, sh1buf, ei, node_s, nullptr,
                                                  W1sw, W2sw, s1, v1, E);
    fin1_kernel<<<((size_t)Nn*78 + 255)/256, 256, 0, stream>>>(node_s, deg, s1, v1, Nn);

    cvt_swz<<<(9*5*64+255)/256,   256, 0, stream>>>(f2W1, f2b1, W1sw, 144, 9, 0);
    cvt_swz<<<(242*5*64+255)/256, 256, 0, stream>>>(f2W2, f2b2, W2sw, 3464, 242, 2);

    conv_kernel<2><<<(E+63)/64, 256, 0, stream>>>(edge_emb, sh1buf, ei, s1, v1,
                                                  W1sw, W2sw, out, nullptr, E);
    fin2_kernel<<<((size_t)Nn*108 + 255)/256, 256, 0, stream>>>(s1, v1, deg, out, Nn);
}

// Round 9
// 494.531 us; speedup vs baseline: 1.0514x; 1.0514x over previous
//
#include <hip/hip_runtime.h>
#include <math.h>

// AAModel round 9: conv with block-cooperative ASYNC LDS staging of W2
// (global_load_lds, 2-tile double buffer carved from the dead ea/hid pool).
// Each wave owns 16 edges (ag[1][5]=20 VGPR) and consumes the SAME LDS tile
// stream -> no per-wave register B-buffers (the 80 VGPR that kept rounds 6-8
// at 2 waves/SIMD and latency-bound on L2). xsT stored bf16; GEMM1 done in
// two M-halves -> LDS ~49KB, VGPR ~140 -> 3 blocks/CU.

constexpr float SQ3f = 1.7320508075688772f;
constexpr float INV1 = 0.14433756729740643f;  // 1/sqrt(48)
constexpr float NAc  = 0.10206207261596575f;  // 1/sqrt(2*48)
constexpr float NBc  = 0.22360679774997896f;  // 1/sqrt(2*10)
constexpr float C20  = 0.22360679774997896f;  // 1/sqrt(20)
constexpr float RATIO= 1.2649110640673518f;   // (NBc/sqrt3)/NAc
constexpr float DSP  = 30.0f/31.0f;
constexpr float GCOEF= -0.5f/(DSP*DSP);

typedef __attribute__((ext_vector_type(8))) short bf16x8;
typedef __attribute__((ext_vector_type(4))) float f32x4;

__device__ __forceinline__ unsigned short f2bf(float x) {
    unsigned u = __builtin_bit_cast(unsigned, x);
    u += 0x7fffu + ((u >> 16) & 1u);     // RNE
    return (unsigned short)(u >> 16);
}
__device__ __forceinline__ float bf2f(unsigned short h) {
    return __builtin_bit_cast(float, ((unsigned)h) << 16);
}

// tile/lane-slot -> original W2 column (or -1 = padding lane)
__device__ __forceinline__ int colmap(int layer, int t, int lm) {
    if (layer == 0) return t*16 + lm;                           // W1 identity
    if (layer == 1) {
        if (t < 144) { const int og=t/48, i=t-og*48; return i*48 + og*16 + lm; }      // w00
        const int i = t-144; return (lm<10) ? 2304 + i*10 + lm : -1;                  // w01
    }
    if (t < 144) { const int og=t/48, i=t-og*48; return i*48 + og*16 + lm; }          // w00
    if (t < 174) { const int s=t-144, og=s/10, i=s-og*10; return 2884 + i*48 + og*16 + lm; } // w11s
    if (t < 222) { const int i=t-174; return (lm<10) ? 2304 + i*10 + lm : -1; }       // w01
    if (t < 232) { const int i=t-222; return (lm<10) ? 2784 + i*10 + lm : -1; }       // w10
    { const int i=t-232; return (lm<10) ? 3364 + i*10 + lm : -1; }                    // w11p
}

__global__ __launch_bounds__(256)
void cvt_swz(const float* __restrict__ W, const float* __restrict__ bias,
             short* __restrict__ Wsw, int ncol, int ntile, int layer)
{
    const int gid = blockIdx.x*256 + threadIdx.x;
    const int g = gid >> 6, lane = gid & 63;
    if (g >= ntile*5) return;
    const int tile = g/5, ks = g - tile*5;
    const int c  = colmap(layer, tile, lane & 15);
    const int k0 = ks*32 + (lane >> 4)*8;
    union { uint4 u4; unsigned short h[8]; } pk;
    #pragma unroll
    for (int j=0;j<8;j++) {
        const int k = k0 + j;
        float v = 0.f;
        if (c >= 0) {
            if (k < 144)       v = W[(size_t)k*ncol + c];
            else if (k == 144) v = bias[c];
        }
        pk.h[j] = f2bf(v);
    }
    *(uint4*)&Wsw[((size_t)g*64 + lane)*8] = pk.u4;
}

// ----------------------------------------------------------------------------
__global__ __launch_bounds__(256)
void edge_kernel(const float* __restrict__ pos, const float* __restrict__ sigma,
                 const int* __restrict__ ei,
                 const float* __restrict__ W1, const float* __restrict__ b1,
                 const float* __restrict__ W2, const float* __restrict__ b2,
                 float* __restrict__ edge_emb, float* __restrict__ sh1buf,
                 int* __restrict__ deg, int E)
{
    __shared__ float inl[4][64];
    __shared__ float hidl[4][48];
    const int w    = threadIdx.x >> 6;
    const int lane = threadIdx.x & 63;
    const int e    = blockIdx.x*4 + w;
    const bool valid = (e < E);
    const int ec = valid ? e : 0;
    const int src = ei[ec], dst = ei[E+ec];
    const float vx = pos[dst*3+0]-pos[src*3+0];
    const float vy = pos[dst*3+1]-pos[src*3+1];
    const float vz = pos[dst*3+2]-pos[src*3+2];
    const float d  = sqrtf(vx*vx+vy*vy+vz*vz);
    const float si = SQ3f/(d+1e-8f);
    const float s0 = vx*si, s1 = vy*si, s2 = vz*si;
    if (lane < 32) {
        inl[w][lane] = sigma[src*32+lane];
    } else {
        const float off  = (float)(lane-32)*DSP;
        const float diff = d - off;
        inl[w][lane] = expf(GCOEF*diff*diff);
    }
    __syncthreads();
    if (lane < 48) {
        float a = b1[lane];
        #pragma unroll 8
        for (int j=0;j<64;j++) a = fmaf(inl[w][j], W1[j*48+lane], a);
        hidl[w][lane] = fmaxf(a, 0.f);
    }
    __syncthreads();
    if (valid) {
        if (lane < 48) {
            float a = b2[lane];
            #pragma unroll 8
            for (int j=0;j<48;j++) a = fmaf(hidl[w][j], W2[j*48+lane], a);
            edge_emb[e*48+lane] = a;
        }
        if (lane == 0) atomicAdd(&deg[dst], 1);
        if (lane < 3)  sh1buf[e*4+lane] = (lane==0)?s0:((lane==1)?s1:s2);
    }
}

// ----------------------------------------------------------------------------
__device__ __forceinline__ void load_bfrag(const short* __restrict__ Wsw,
                                           int tile, int lane, bf16x8 (&b)[5]) {
    #pragma unroll
    for (int ks=0; ks<5; ks++)
        b[ks] = *(const bf16x8*)&Wsw[((size_t)(tile*5+ks)*64 + lane)*8];
}

// ----------------------------------------------------------------------------
template<int LAYER>
__global__ __launch_bounds__(256)
void conv_kernel(const float* __restrict__ edge_emb, const float* __restrict__ sh1buf,
                 const int* __restrict__ ei,
                 const float* __restrict__ sin_, const float* __restrict__ vin,
                 const short* __restrict__ W1sw, const short* __restrict__ W2sw,
                 float* __restrict__ outS, float* __restrict__ outV, int E)
{
    constexpr int NT = (LAYER==1) ? 192 : 242;
    constexpr int NG = NT/2;                 // 2-tile stage groups

    // pool: ea (24KB, swizzled bf16) -> hid (20KB) -> W2 stage dbuf (2x10KB)
    __shared__ __align__(16) short pool[64*192];
    __shared__ __align__(16) unsigned short xsTb[48][64];   // bf16 xs, [chan][edge]
    __shared__ float sh1l[64][4];
    __shared__ int   srcl[64], dstl[64];
    __shared__ __align__(16) float xvT[LAYER==2 ? 30 : 1][64];
    __shared__ __align__(16) float uT [LAYER==2 ? 10 : 1][64];
    __shared__ __align__(16) float cvT[LAYER==2 ? 30 : 1][64];

    const int t  = threadIdx.x;
    const int eb = blockIdx.x * 64;

    if (t < 64) {
        const int ge = eb + t; const int gc = (ge < E) ? ge : (E-1);
        srcl[t] = ei[gc]; dstl[t] = ei[E+gc];
    }
    {
        const int e = t >> 2, k = t & 3;
        const int ge = eb + e; const int gc = (ge<E)?ge:(E-1);
        sh1l[e][k] = sh1buf[gc*4 + k];
    }
    __syncthreads();

    // ---- stage ea -> bf16 swizzled pool (+ bf16 xsT fill)
    for (int p = t; p < 64*24; p += 256) {
        const int m = p / 24, s = p - m*24;
        const int k0 = s*8;
        float vals[8] = {0.f,0.f,0.f,0.f,0.f,0.f,0.f,0.f};
        if (k0 < 48) {
            const int ge = eb + m; const int gc = (ge<E)?ge:(E-1);
            const float4 a = *(const float4*)&edge_emb[gc*48 + k0];
            const float4 b = *(const float4*)&edge_emb[gc*48 + k0 + 4];
            vals[0]=a.x; vals[1]=a.y; vals[2]=a.z; vals[3]=a.w;
            vals[4]=b.x; vals[5]=b.y; vals[6]=b.z; vals[7]=b.w;
        } else if (k0 < 96) {
            const float4 a = *(const float4*)&sin_[srcl[m]*48 + (k0-48)];
            const float4 b = *(const float4*)&sin_[srcl[m]*48 + (k0-48) + 4];
            vals[0]=a.x; vals[1]=a.y; vals[2]=a.z; vals[3]=a.w;
            vals[4]=b.x; vals[5]=b.y; vals[6]=b.z; vals[7]=b.w;
        } else if (k0 < 144) {
            const float4 a = *(const float4*)&sin_[dstl[m]*48 + (k0-96)];
            const float4 b = *(const float4*)&sin_[dstl[m]*48 + (k0-96) + 4];
            vals[0]=a.x; vals[1]=a.y; vals[2]=a.z; vals[3]=a.w;
            vals[4]=b.x; vals[5]=b.y; vals[6]=b.z; vals[7]=b.w;
        } else if (k0 == 144) {
            vals[0] = 1.f;                       // bias row for GEMM1
        }
        union { uint4 u4; unsigned short h[8]; } pk;
        #pragma unroll
        for (int j=0;j<8;j++) pk.h[j] = f2bf(vals[j]);
        *(uint4*)&pool[m*192 + ((s ^ (m&7))*8)] = pk.u4;
        if (k0 >= 48 && k0 < 96) {
            #pragma unroll
            for (int j=0;j<8;j++) xsTb[k0-48+j][m] = pk.h[j];
        }
    }
    if (LAYER==2) {
        for (int p=t; p<640; p+=256) {
            const int i = p >> 6, e = p & 63;
            const float x0 = vin[srcl[e]*30 + i*3+0];
            const float x1 = vin[srcl[e]*30 + i*3+1];
            const float x2 = vin[srcl[e]*30 + i*3+2];
            const float h0=sh1l[e][0], h1=sh1l[e][1], h2=sh1l[e][2];
            xvT[i*3+0][e]=x0; xvT[i*3+1][e]=x1; xvT[i*3+2][e]=x2;
            uT[i][e] = x0*h0 + x1*h1 + x2*h2;
            cvT[i*3+0][e] = x1*h2 - x2*h1;
            cvT[i*3+1][e] = x2*h0 - x0*h2;
            cvT[i*3+2][e] = x0*h1 - x1*h0;
        }
    }
    __syncthreads();

    const int wv = t >> 6, lane = t & 63;
    const int lm = lane & 15, lk = lane >> 4, lk4 = lk*4;

    // ---- GEMM1 in two M-halves (peak ~130 VGPR): hid = relu(ea @ W1)
    f32x4 aa[3][2], ab[3][2];   // [j][mt-in-half]
    {
        bf16x8 af[2][5];
        #pragma unroll
        for (int mt=0; mt<2; mt++) {
            const int m = mt*16 + lm;
            #pragma unroll
            for (int ks=0; ks<5; ks++)
                af[mt][ks] = *(const bf16x8*)&pool[m*192 + (((ks*4+lk) ^ (m&7))*8)];
        }
        #pragma unroll
        for (int j=0; j<3; j++) {
            const int nt = wv + j*4;
            if (nt < 9) {
                bf16x8 bw[5];
                load_bfrag(W1sw, nt, lane, bw);
                #pragma unroll
                for (int mt=0; mt<2; mt++) aa[j][mt] = (f32x4){0.f,0.f,0.f,0.f};
                #pragma unroll
                for (int ks=0; ks<5; ks++)
                    #pragma unroll
                    for (int mt=0; mt<2; mt++)
                        aa[j][mt] = __builtin_amdgcn_mfma_f32_16x16x32_bf16(af[mt][ks], bw[ks], aa[j][mt], 0,0,0);
            }
        }
        #pragma unroll
        for (int mt=0; mt<2; mt++) {
            const int m = (mt+2)*16 + lm;
            #pragma unroll
            for (int ks=0; ks<5; ks++)
                af[mt][ks] = *(const bf16x8*)&pool[m*192 + (((ks*4+lk) ^ (m&7))*8)];
        }
        #pragma unroll
        for (int j=0; j<3; j++) {
            const int nt = wv + j*4;
            if (nt < 9) {
                bf16x8 bw[5];
                load_bfrag(W1sw, nt, lane, bw);
                #pragma unroll
                for (int mt=0; mt<2; mt++) ab[j][mt] = (f32x4){0.f,0.f,0.f,0.f};
                #pragma unroll
                for (int ks=0; ks<5; ks++)
                    #pragma unroll
                    for (int mt=0; mt<2; mt++)
                        ab[j][mt] = __builtin_amdgcn_mfma_f32_16x16x32_bf16(af[mt][ks], bw[ks], ab[j][mt], 0,0,0);
            }
        }
    }
    __syncthreads();   // all ea reads done; overwrite pool with hid
    #pragma unroll
    for (int j=0; j<3; j++) {
        const int nt = wv + j*4;
        if (nt < 9) {
            const int c = nt*16 + lm;
            #pragma unroll
            for (int mt=0; mt<4; mt++) {
                const f32x4 v = (mt<2) ? aa[j][mt] : ab[j][mt-2];
                #pragma unroll
                for (int r=0; r<4; r++) {
                    const int m = mt*16 + lk4 + r;
                    pool[m*192 + (((c>>3) ^ (m&7))*8) + (c&7)] = (short)f2bf(fmaxf(v[r], 0.f));
                }
            }
        }
    }
    if (t < 128) {  // bias rows k=144..159
        const int m = t >> 1, s = 18 + (t & 1);
        union { uint4 u4; unsigned short h[8]; } pk;
        pk.u4.x = pk.u4.y = pk.u4.z = pk.u4.w = 0u;
        if (s == 18) pk.h[0] = f2bf(1.f);
        *(uint4*)&pool[m*192 + ((s ^ (m&7))*8)] = pk.u4;
    }
    __syncthreads();

    // ---- each wave loads its OWN m-tile A-fragment (16 edges)
    bf16x8 ag[5];
    {
        const int m = wv*16 + lm;
        #pragma unroll
        for (int ks=0; ks<5; ks++)
            ag[ks] = *(const bf16x8*)&pool[m*192 + (((ks*4+lk) ^ (m&7))*8)];
    }
    __syncthreads();   // pool now free -> W2 stage double buffer

    // ---- async staging machinery (2 tiles = 10240B per group)
    auto STAGE = [&](int bufsel, int g) {
        const char* gsrc = (const char*)W2sw + (size_t)g*10240;
        char* lbase = (char*)pool + bufsel*10240;
        for (int c = wv; c < 10; c += 4) {
            __builtin_amdgcn_global_load_lds(
                (const __attribute__((address_space(1))) void*)(gsrc + c*1024 + lane*16),
                (__attribute__((address_space(3))) void*)(lbase + c*1024),
                16, 0, 0);
        }
    };

    int gstage = 1, cur = 0;
    STAGE(0, 0);
    __syncthreads();   // drain (syncthreads waits vmcnt 0) + all waves ready

    const int col0 = wv*16 + lk4;

    // per-region runner: count tiles (even), region-local index -> upd
    auto runpairs = [&](int count, auto&& upd) {
        for (int i = 0; i < count; i += 2) {
            if (gstage < NG) { STAGE(cur^1, gstage); ++gstage; }
            const short* tb = pool + cur*5120;
            #pragma unroll
            for (int s = 0; s < 2; ++s) {
                bf16x8 bf_[5];
                #pragma unroll
                for (int ks=0; ks<5; ks++)
                    bf_[ks] = *(const bf16x8*)&tb[s*2560 + ks*512 + lane*8];
                f32x4 a = (f32x4){0.f,0.f,0.f,0.f};
                #pragma unroll
                for (int ks=0; ks<5; ks++)
                    a = __builtin_amdgcn_mfma_f32_16x16x32_bf16(ag[ks], bf_[ks], a, 0,0,0);
                upd(i+s, a);
            }
            __syncthreads();   // drains staged loads + protects buffer swap
            cur ^= 1;
        }
    };

    float ms0[4]={0,0,0,0}, ms1[4]={0,0,0,0}, ms2[4]={0,0,0,0}, vc[4]={0,0,0,0};
    float m3[4][3] = {};
    float p3[4][3] = {};

    auto upd_ms = [&](float (&ms)[4], int i, const f32x4& a, float scale) {
        const ushort4 xw = *(const ushort4*)&xsTb[i][col0];
        ms[0] = fmaf(a[0]*scale, bf2f(xw.x), ms[0]);
        ms[1] = fmaf(a[1]*scale, bf2f(xw.y), ms[1]);
        ms[2] = fmaf(a[2]*scale, bf2f(xw.z), ms[2]);
        ms[3] = fmaf(a[3]*scale, bf2f(xw.w), ms[3]);
    };

    // region sequence (tile bases contiguous; all counts even)
    runpairs(48, [&](int i, const f32x4& a){ upd_ms(ms0, i, a, 1.f); });
    runpairs(48, [&](int i, const f32x4& a){ upd_ms(ms1, i, a, 1.f); });
    runpairs(48, [&](int i, const f32x4& a){ upd_ms(ms2, i, a, 1.f); });
    if (LAYER==2) {
        runpairs(10, [&](int i, const f32x4& a){
            const f32x4 u = *(const f32x4*)&uT[i][col0];
            #pragma unroll
            for (int r=0;r<4;r++) ms0[r] = fmaf(a[r]*RATIO, u[r], ms0[r]);
        });
        runpairs(10, [&](int i, const f32x4& a){
            const f32x4 u = *(const f32x4*)&uT[i][col0];
            #pragma unroll
            for (int r=0;r<4;r++) ms1[r] = fmaf(a[r]*RATIO, u[r], ms1[r]);
        });
        runpairs(10, [&](int i, const f32x4& a){
            const f32x4 u = *(const f32x4*)&uT[i][col0];
            #pragma unroll
            for (int r=0;r<4;r++) ms2[r] = fmaf(a[r]*RATIO, u[r], ms2[r]);
        });
    }
    runpairs(48, [&](int i, const f32x4& a){ upd_ms(vc, i, a, 1.f); });
    if (LAYER==2) {
        runpairs(10, [&](int i, const f32x4& a){
            #pragma unroll
            for (int d=0; d<3; d++) {
                const f32x4 x = *(const f32x4*)&xvT[i*3+d][col0];
                #pragma unroll
                for (int r=0;r<4;r++) m3[r][d] = fmaf(a[r], x[r], m3[r][d]);
            }
        });
        runpairs(10, [&](int i, const f32x4& a){
            #pragma unroll
            for (int d=0; d<3; d++) {
                const f32x4 x = *(const f32x4*)&cvT[i*3+d][col0];
                #pragma unroll
                for (int r=0;r<4;r++) p3[r][d] = fmaf(a[r], x[r], p3[r][d]);
            }
        });
    }

    // ---- scatter (per wave: its 16 edges)
    const float sScale = (LAYER==1) ? INV1 : NAc;
    const int   sStrd  = (LAYER==1) ? 48 : 108;
    #pragma unroll
    for (int r=0;r<4;r++) {
        const int e = wv*16 + lk4 + r;
        if (eb+e < E) {
            const size_t base = (size_t)dstl[e]*sStrd;
            unsafeAtomicAdd(&outS[base + 0*16 + lm], ms0[r]*sScale);
            unsafeAtomicAdd(&outS[base + 1*16 + lm], ms1[r]*sScale);
            unsafeAtomicAdd(&outS[base + 2*16 + lm], ms2[r]*sScale);
        }
    }
    if (lm < 10) {
        #pragma unroll
        for (int r=0;r<4;r++) {
            const int e = wv*16 + lk4 + r;
            if (eb+e < E) {
                if (LAYER==1) {
                    const float v = vc[r]*INV1;
                    #pragma unroll
                    for (int d=0; d<3; d++)
                        unsafeAtomicAdd(&outV[(size_t)dstl[e]*30 + lm*3 + d], v*sh1l[e][d]);
                } else {
                    const float v = vc[r]*NAc;
                    const size_t base = (size_t)dstl[e]*108;
                    #pragma unroll
                    for (int d=0; d<3; d++) {
                        unsafeAtomicAdd(&outS[base + 48 + lm*3 + d], v*sh1l[e][d] + m3[r][d]*NBc);
                        unsafeAtomicAdd(&outS[base + 78 + lm*3 + d], p3[r][d]*C20);
                    }
                }
            }
        }
    }
}

// ----------------------------------------------------------------------------
__global__ __launch_bounds__(256)
void fin1_kernel(const float* __restrict__ node_s, const int* __restrict__ deg,
                 float* __restrict__ s1, float* __restrict__ v1, int Nn)
{
    const int p = blockIdx.x*256 + threadIdx.x;
    const int totS = Nn*48;
    if (p < totS) {
        const int n = p/48;
        const int dgi = deg[n];
        const float dg = (float)(dgi > 1 ? dgi : 1);
        s1[p] = node_s[p] + s1[p]/dg;
    } else {
        const int q = p - totS;
        if (q < Nn*30) {
            const int n = q/30;
            const int dgi = deg[n];
            const float dg = (float)(dgi > 1 ? dgi : 1);
            v1[q] = v1[q]/dg;
        }
    }
}

__global__ __launch_bounds__(256)
void fin2_kernel(const float* __restrict__ s1, const float* __restrict__ v1,
                 const int* __restrict__ deg, float* __restrict__ out, int Nn)
{
    const int p = blockIdx.x*256 + threadIdx.x;
    if (p >= Nn*108) return;
    const int n = p/108, c = p - n*108;
    const int dgi = deg[n];
    const float dg = (float)(dgi > 1 ? dgi : 1);
    const float acc = out[p]/dg;
    if (c < 48)      out[p] = s1[n*48+c] + acc;
    else if (c < 78) out[p] = v1[n*30 + (c-48)] + acc;
    else             out[p] = acc;
}

// ----------------------------------------------------------------------------
extern "C" void kernel_launch(void* const* d_in, const int* in_sizes, int n_in,
                              void* d_out, int out_size, void* d_ws, size_t ws_size,
                              hipStream_t stream)
{
    const float* pos    = (const float*)d_in[0];
    const float* sigma  = (const float*)d_in[1];
    const float* node_s = (const float*)d_in[2];
    const float* eW1  = (const float*)d_in[3];
    const float* eb1  = (const float*)d_in[4];
    const float* eW2  = (const float*)d_in[5];
    const float* eb2  = (const float*)d_in[6];
    const float* f1W1 = (const float*)d_in[7];
    const float* f1b1 = (const float*)d_in[8];
    const float* f1W2 = (const float*)d_in[9];
    const float* f1b2 = (const float*)d_in[10];
    const float* f2W1 = (const float*)d_in[11];
    const float* f2b1 = (const float*)d_in[12];
    const float* f2W2 = (const float*)d_in[13];
    const float* f2b2 = (const float*)d_in[14];
    const int*   ei   = (const int*)d_in[15];
    const int Nn = in_sizes[0]/3;
    const int E  = in_sizes[15]/2;
    float* out = (float*)d_out;

    char* ws = (char*)d_ws;
    float* edge_emb = (float*)ws;  ws += (size_t)E*48*sizeof(float);
    float* sh1buf   = (float*)ws;  ws += (size_t)E*4*sizeof(float);
    float* s1       = (float*)ws;  ws += (size_t)Nn*48*sizeof(float);
    float* v1       = (float*)ws;  ws += (size_t)Nn*30*sizeof(float);
    int*   deg      = (int*)ws;    ws += (size_t)Nn*sizeof(int);
    short* W1sw     = (short*)ws;  ws += (size_t)9*5*64*8*sizeof(short);
    short* W2sw     = (short*)ws;  ws += (size_t)242*5*64*8*sizeof(short);

    hipMemsetAsync(s1,  0, (size_t)Nn*48*sizeof(float), stream);
    hipMemsetAsync(v1,  0, (size_t)Nn*30*sizeof(float), stream);
    hipMemsetAsync(deg, 0, (size_t)Nn*sizeof(int),      stream);
    hipMemsetAsync(out, 0, (size_t)Nn*108*sizeof(float), stream);

    edge_kernel<<<(E+3)/4, 256, 0, stream>>>(pos, sigma, ei, eW1, eb1, eW2, eb2,
                                             edge_emb, sh1buf, deg, E);

    cvt_swz<<<(9*5*64+255)/256,   256, 0, stream>>>(f1W1, f1b1, W1sw, 144, 9, 0);
    cvt_swz<<<(192*5*64+255)/256, 256, 0, stream>>>(f1W2, f1b2, W2sw, 2784, 192, 1);

    conv_kernel<1><<<(E+63)/64, 256, 0, stream>>>(edge_emb, sh1buf, ei, node_s, nullptr,
                                                  W1sw, W2sw, s1, v1, E);
    fin1_kernel<<<((size_t)Nn*78 + 255)/256, 256, 0, stream>>>(node_s, deg, s1, v1, Nn);

    cvt_swz<<<(9*5*64+255)/256,   256, 0, stream>>>(f2W1, f2b1, W1sw, 144, 9, 0);
    cvt_swz<<<(242*5*64+255)/256, 256, 0, stream>>>(f2W2, f2b2, W2sw, 3464, 242, 2);

    conv_kernel<2><<<(E+63)/64, 256, 0, stream>>>(edge_emb, sh1buf, ei, s1, v1,
                                                  W1sw, W2sw, out, nullptr, E);
    fin2_kernel<<<((size_t)Nn*108 + 255)/256, 256, 0, stream>>>(s1, v1, deg, out, Nn);
}